// Round 1
// baseline (1000.725 us; speedup 1.0000x reference)
//
#include <hip/hip_runtime.h>
#include <cstdint>
#include <cstddef>

#define NB 16
#define T_ 2048
#define D_ 512
#define F_ 2048

using f16 = _Float16;
typedef __attribute__((ext_vector_type(8))) f16 f16x8;
typedef __attribute__((ext_vector_type(4))) f16 f16x4;
typedef __attribute__((ext_vector_type(4))) float f32x4;

// ---------------- async global->LDS (16B per lane, wave-uniform LDS base) ----
__device__ __forceinline__ void g2l16(const f16* g, f16* l) {
  __builtin_amdgcn_global_load_lds((const __attribute__((address_space(1))) void*)g,
                                   (__attribute__((address_space(3))) void*)l,
                                   16, 0, 0);
}

// ---------------- 128x128 GEMM core ----------------------------------------
// A: 128 rows of (lda-stride) f16, K-contiguous. Bt: 128 rows (= output cols)
// of (ldb-stride) f16, K-contiguous. acc[4][4] per wave; waves 2x2, 64x64 each.
// LDS tile layout: linear [row][kslot] with kslot XOR-swizzled by ((row>>1)&3)
// (16B granules). global_load_lds writes linearly; the swizzle is applied on
// the per-lane GLOBAL source address; ds_read applies the same XOR.
__device__ __forceinline__ void gemm_core_128(
    const f16* __restrict__ Ab, int lda,
    const f16* __restrict__ Bb, int ldb,
    int K, f16* sA, f16* sB, f32x4 (&acc)[4][4])
{
  const int tid = threadIdx.x;
  const int w = tid >> 6, lane = tid & 63;
  // staging geometry: 8KB tile = 4 waves x 2 issues x 64 lanes x 16B
  const int o0 = (w*2+0)*1024 + lane*16;
  const int o1 = (w*2+1)*1024 + lane*16;
  const int r0 = o0 >> 6, r1 = o1 >> 6;              // row 0..127
  const int s0 = ((o0>>4)&3) ^ ((r0>>1)&3);          // logical k-slot (pre-swizzled source)
  const int s1 = ((o1>>4)&3) ^ ((r1>>1)&3);
  const size_t gaoff0 = (size_t)r0*lda + s0*8;
  const size_t gaoff1 = (size_t)r1*lda + s1*8;
  const size_t gboff0 = (size_t)r0*ldb + s0*8;
  const size_t gboff1 = (size_t)r1*ldb + s1*8;

  g2l16(Ab + gaoff0, sA + (w*2+0)*512);
  g2l16(Ab + gaoff1, sA + (w*2+1)*512);
  g2l16(Bb + gboff0, sB + (w*2+0)*512);
  g2l16(Bb + gboff1, sB + (w*2+1)*512);
  __syncthreads();

  const int wm = w >> 1, wn = w & 1;
  const int lr = lane & 15, ks = lane >> 4;
  int offA[4], offB[4];
  #pragma unroll
  for (int i = 0; i < 4; ++i) {
    int row = wm*64 + i*16 + lr;
    offA[i] = row*64 + ((ks ^ ((row>>1)&3)) << 4);
    int col = wn*64 + i*16 + lr;
    offB[i] = col*64 + ((ks ^ ((col>>1)&3)) << 4);
  }

  const int nk = K >> 5;
  int buf = 0;
  for (int kt = 0; kt < nk; ++kt) {
    if (kt + 1 < nk) {
      const f16* An = Ab + (kt+1)*32;
      const f16* Bn = Bb + (kt+1)*32;
      f16* dA = sA + (buf^1)*4096;
      f16* dB = sB + (buf^1)*4096;
      g2l16(An + gaoff0, dA + (w*2+0)*512);
      g2l16(An + gaoff1, dA + (w*2+1)*512);
      g2l16(Bn + gboff0, dB + (w*2+0)*512);
      g2l16(Bn + gboff1, dB + (w*2+1)*512);
    }
    const char* pA = (const char*)(sA + buf*4096);
    const char* pB = (const char*)(sB + buf*4096);
    f16x8 af[4], bf[4];
    #pragma unroll
    for (int i = 0; i < 4; ++i) {
      af[i] = *(const f16x8*)(pA + offA[i]);
      bf[i] = *(const f16x8*)(pB + offB[i]);
    }
    #pragma unroll
    for (int mi = 0; mi < 4; ++mi)
      #pragma unroll
      for (int ni = 0; ni < 4; ++ni)
        acc[mi][ni] = __builtin_amdgcn_mfma_f32_16x16x32_f16(af[mi], bf[ni], acc[mi][ni], 0, 0, 0);
    __syncthreads();
    buf ^= 1;
  }
}

// EPI: 0 = +bias -> f16 store ; 1 = +bias, exact-erf GELU -> f16 ; 2 = +bias + C(f32) -> C(f32)
template<int EPI>
__global__ __launch_bounds__(256, 2) void gemm_kernel(
    const f16* __restrict__ A, int lda,
    const f16* __restrict__ Bt, int ldb,
    void* __restrict__ Cv, int ldc,
    const float* __restrict__ bias, int K)
{
  __shared__ __align__(16) f16 sA[2*4096];
  __shared__ __align__(16) f16 sB[2*4096];
  const int m0 = blockIdx.x * 128, n0 = blockIdx.y * 128;
  f32x4 acc[4][4];
  #pragma unroll
  for (int i = 0; i < 4; ++i)
    #pragma unroll
    for (int j = 0; j < 4; ++j) acc[i][j] = f32x4{0.f, 0.f, 0.f, 0.f};
  gemm_core_128(A + (size_t)m0*lda, lda, Bt + (size_t)n0*ldb, ldb, K, sA, sB, acc);

  const int w = threadIdx.x >> 6, lane = threadIdx.x & 63;
  const int wm = w >> 1, wn = w & 1, lr = lane & 15, lq = lane >> 4;
  #pragma unroll
  for (int mi = 0; mi < 4; ++mi) {
    #pragma unroll
    for (int ni = 0; ni < 4; ++ni) {
      int col = n0 + wn*64 + ni*16 + lr;
      float bv = bias[col];
      int rbase = m0 + wm*64 + mi*16 + lq*4;
      #pragma unroll
      for (int r = 0; r < 4; ++r) {
        float val = acc[mi][ni][r] + bv;
        size_t o = (size_t)(rbase + r)*ldc + col;
        if (EPI == 0) {
          ((f16*)Cv)[o] = (f16)val;
        } else if (EPI == 1) {
          val = 0.5f * val * (1.f + erff(val * 0.70710678118654752f));
          ((f16*)Cv)[o] = (f16)val;
        } else {
          float* Cf = (float*)Cv;
          Cf[o] = Cf[o] + val;
        }
      }
    }
  }
}

// score[b,tau] += sum of diagonal tau of S = Q K^T (lower triangle only)
__global__ __launch_bounds__(256, 2) void score_kernel(
    const f16* __restrict__ qkv, float* __restrict__ score)
{
  const int tj = blockIdx.x, ti = blockIdx.y, b = blockIdx.z;
  if (ti < tj) return;
  __shared__ __align__(16) f16 sA[2*4096];
  __shared__ __align__(16) f16 sB[2*4096];
  __shared__ float diag[255];
  const f16* Ab = qkv + ((size_t)b*T_ + (size_t)ti*128)*1536;        // Q
  const f16* Bb = qkv + ((size_t)b*T_ + (size_t)tj*128)*1536 + 512;  // K
  f32x4 acc[4][4];
  #pragma unroll
  for (int i = 0; i < 4; ++i)
    #pragma unroll
    for (int j = 0; j < 4; ++j) acc[i][j] = f32x4{0.f, 0.f, 0.f, 0.f};
  gemm_core_128(Ab, 1536, Bb, 1536, 512, sA, sB, acc);

  for (int i = threadIdx.x; i < 255; i += 256) diag[i] = 0.f;
  __syncthreads();
  const int w = threadIdx.x >> 6, lane = threadIdx.x & 63;
  const int wm = w >> 1, wn = w & 1, lr = lane & 15, lq = lane >> 4;
  const bool dg = (ti == tj);
  #pragma unroll
  for (int mi = 0; mi < 4; ++mi) {
    #pragma unroll
    for (int ni = 0; ni < 4; ++ni) {
      int jloc = wn*64 + ni*16 + lr;
      int ibase = wm*64 + mi*16 + lq*4;
      #pragma unroll
      for (int r = 0; r < 4; ++r) {
        int iloc = ibase + r;
        if (!dg || iloc >= jloc) atomicAdd(&diag[iloc - jloc + 127], acc[mi][ni][r]);
      }
    }
  }
  __syncthreads();
  for (int i = threadIdx.x; i < 255; i += 256) {
    int tau = (ti - tj)*128 + i - 127;
    if (tau >= 1 && tau < T_) atomicAdd(&score[(size_t)b*T_ + tau], diag[i]);
  }
}

__global__ void topk_kernel(const float* __restrict__ score, int* __restrict__ lags)
{
  const int b = blockIdx.x, tid = threadIdx.x;
  __shared__ float vals[T_];
  __shared__ float rmax[256];
  __shared__ int   rarg[256];
  __shared__ int   outk[8];
  for (int t = tid; t < T_; t += 256) vals[t] = (t == 0) ? -1e30f : score[(size_t)b*T_ + t];
  __syncthreads();
  for (int k = 0; k < 8; ++k) {
    float m = -1e30f; int mi = 0x7fffffff;
    for (int t = tid; t < T_; t += 256) {
      float v = vals[t];
      if (v > m || (v == m && t < mi)) { m = v; mi = t; }
    }
    rmax[tid] = m; rarg[tid] = mi;
    __syncthreads();
    for (int s = 128; s > 0; s >>= 1) {
      if (tid < s) {
        float v2 = rmax[tid+s]; int i2 = rarg[tid+s];
        if (v2 > rmax[tid] || (v2 == rmax[tid] && i2 < rarg[tid])) { rmax[tid] = v2; rarg[tid] = i2; }
      }
      __syncthreads();
    }
    if (tid == 0) { outk[k] = rarg[0]; vals[rarg[0]] = -1e30f; }
    __syncthreads();
  }
  if (tid < 8) lags[b*8 + tid] = outk[tid];
}

// trend1 = movavg25(x) -> out_trend ; s1 = x - trend1 -> f16
__global__ void decomp1_kernel(const float* __restrict__ x,
                               float* __restrict__ trend1, f16* __restrict__ s16)
{
  int idx = blockIdx.x*256 + threadIdx.x;              // (b, t, d4)
  int d4 = idx & 127, t = (idx >> 7) & (T_-1), b = idx >> 18;
  const float* xb = x + ((size_t)b*T_)*D_ + d4*4;
  f32x4 sum = {0.f,0.f,0.f,0.f};
  f32x4 center = {0.f,0.f,0.f,0.f};
  #pragma unroll
  for (int j = -12; j <= 12; ++j) {
    int tt = t + j; tt = tt < 0 ? 0 : (tt > T_-1 ? T_-1 : tt);
    f32x4 v = *(const f32x4*)(xb + (size_t)tt*D_);
    sum += v;
    if (j == 0) center = v;
  }
  f32x4 tr = sum * (1.f/25.f);
  size_t o = ((size_t)(b*T_ + t))*D_ + d4*4;
  *(f32x4*)(trend1 + o) = tr;
  f32x4 s = center - tr;
  f16x4 h;
  #pragma unroll
  for (int i = 0; i < 4; ++i) h[i] = (f16)s[i];
  *(f16x4*)(s16 + o) = h;
}

// sac16 (act0, f16): trend2 = movavg25 ; s2 = sac - trend2 -> seas(f32) + s2_16 ;
// trend_io += trend2
__global__ void decomp2_kernel(const f16* __restrict__ sac,
                               float* __restrict__ seas, float* __restrict__ trend_io,
                               f16* __restrict__ s2_16)
{
  int idx = blockIdx.x*256 + threadIdx.x;
  int d4 = idx & 127, t = (idx >> 7) & (T_-1), b = idx >> 18;
  const f16* sb = sac + ((size_t)b*T_)*D_ + d4*4;
  f32x4 sum = {0.f,0.f,0.f,0.f};
  f32x4 center = {0.f,0.f,0.f,0.f};
  #pragma unroll
  for (int j = -12; j <= 12; ++j) {
    int tt = t + j; tt = tt < 0 ? 0 : (tt > T_-1 ? T_-1 : tt);
    f16x4 v = *(const f16x4*)(sb + (size_t)tt*D_);
    f32x4 vf = { (float)v[0], (float)v[1], (float)v[2], (float)v[3] };
    sum += vf;
    if (j == 0) center = vf;
  }
  f32x4 tr = sum * (1.f/25.f);
  size_t o = ((size_t)(b*T_ + t))*D_ + d4*4;
  f32x4 s = center - tr;
  *(f32x4*)(seas + o) = s;
  f16x4 h;
  #pragma unroll
  for (int i = 0; i < 4; ++i) h[i] = (f16)s[i];
  *(f16x4*)(s2_16 + o) = h;
  f32x4 told = *(const f32x4*)(trend_io + o);
  *(f32x4*)(trend_io + o) = told + tr;
}

// act0 := s1_16 + (1/8) sum_k v[(t - lag_k) mod T]   (in-place, element-wise)
__global__ void gather_kernel(const f16* __restrict__ qkv, f16* __restrict__ act,
                              const int* __restrict__ lags)
{
  int idx = blockIdx.x*256 + threadIdx.x;              // (b, t, d8)
  int d8 = idx & 63, t = (idx >> 6) & (T_-1), b = idx >> 17;
  const f16* vb = qkv + (size_t)b*T_*1536 + 1024 + d8*8;
  f16* ap = act + ((size_t)(b*T_ + t))*D_ + d8*8;
  f16x8 s = *(const f16x8*)ap;
  float a[8];
  #pragma unroll
  for (int j = 0; j < 8; ++j) a[j] = (float)s[j];
  #pragma unroll
  for (int k = 0; k < 8; ++k) {
    int lag = lags[b*8 + k];
    int tt = (t - lag + T_) & (T_-1);
    f16x8 v = *(const f16x8*)(vb + (size_t)tt*1536);
    #pragma unroll
    for (int j = 0; j < 8; ++j) a[j] += 0.125f * (float)v[j];
  }
  f16x8 o;
  #pragma unroll
  for (int j = 0; j < 8; ++j) o[j] = (f16)a[j];
  *(f16x8*)ap = o;
}

// convert weights to f16, transposed to (N x K) row-major; concat qkv biases
__global__ void prepack_kernel(const float* __restrict__ Wq, const float* __restrict__ Wk,
                               const float* __restrict__ Wv, const float* __restrict__ bq,
                               const float* __restrict__ bk, const float* __restrict__ bv,
                               const float* __restrict__ W1, const float* __restrict__ W2,
                               f16* __restrict__ wcat, f16* __restrict__ w1t,
                               f16* __restrict__ w2t, float* __restrict__ bcat)
{
  int i = blockIdx.x*256 + threadIdx.x;
  if (i < 786432) {                       // wcat: 1536 x 512
    int n = i >> 9, k = i & 511;
    int sel = n >> 9, nn = n & 511;
    const float* W = sel == 0 ? Wq : (sel == 1 ? Wk : Wv);
    wcat[i] = (f16)W[k*512 + nn];
  } else if (i < 1835008) {               // w1t: 2048 x 512
    int j = i - 786432;
    int n = j >> 9, k = j & 511;
    w1t[j] = (f16)W1[k*2048 + n];
  } else if (i < 2883584) {               // w2t: 512 x 2048
    int j = i - 1835008;
    int n = j >> 11, k = j & 2047;
    w2t[j] = (f16)W2[k*512 + n];
  } else if (i < 2885120) {               // bcat: 1536
    int j = i - 2883584;
    bcat[j] = j < 512 ? bq[j] : (j < 1024 ? bk[j-512] : bv[j-1024]);
  }
}

extern "C" void kernel_launch(void* const* d_in, const int* in_sizes, int n_in,
                              void* d_out, int out_size, void* d_ws, size_t ws_size,
                              hipStream_t stream)
{
  const float* x  = (const float*)d_in[0];
  const float* Wq = (const float*)d_in[1];
  const float* bq = (const float*)d_in[2];
  const float* Wk = (const float*)d_in[3];
  const float* bk = (const float*)d_in[4];
  const float* Wv = (const float*)d_in[5];
  const float* bv = (const float*)d_in[6];
  const float* W1 = (const float*)d_in[7];
  const float* b1 = (const float*)d_in[8];
  const float* W2 = (const float*)d_in[9];
  const float* b2 = (const float*)d_in[10];

  float* out_seas  = (float*)d_out;
  float* out_trend = out_seas + (size_t)NB*T_*D_;

  char* ws = (char*)d_ws;
  f16*   act0  = (f16*)(ws);                        //  32 MB: s1_16 -> sac16 (in place)
  f16*   qkv   = (f16*)(ws + 33554432ull);          //  96 MB: [q|k|v] rows of 1536
  f16*   s2_16 = qkv;                               //  reuse (qkv dead after gather)
  f16*   h16   = (f16*)(ws + 134217728ull);         //  64 MB: FFN hidden (2 chunks)
  f16*   wcat  = (f16*)(ws + 201326592ull);
  f16*   w1t   = (f16*)(ws + 202899456ull);
  f16*   w2t   = (f16*)(ws + 204996608ull);
  float* bcat  = (float*)(ws + 207093760ull);
  float* score = (float*)(ws + 207099904ull);
  int*   lags  = (int*)(ws + 207230976ull);

  (void)hipMemsetAsync(score, 0, (size_t)NB*T_*sizeof(float), stream);
  prepack_kernel<<<11270, 256, 0, stream>>>(Wq, Wk, Wv, bq, bk, bv, W1, W2,
                                            wcat, w1t, w2t, bcat);
  decomp1_kernel<<<NB*T_*(D_/4)/256, 256, 0, stream>>>(x, out_trend, act0);
  // QKV: (32768 x 512) @ (512 x 1536) -> qkv f16
  gemm_kernel<0><<<dim3(32768/128, 1536/128), 256, 0, stream>>>(
      act0, 512, wcat, 512, qkv, 1536, bcat, 512);
  score_kernel<<<dim3(16, 16, NB), 256, 0, stream>>>(qkv, score);
  topk_kernel<<<NB, 256, 0, stream>>>(score, lags);
  gather_kernel<<<NB*T_*(D_/8)/256, 256, 0, stream>>>(qkv, act0, lags);
  decomp2_kernel<<<NB*T_*(D_/4)/256, 256, 0, stream>>>(act0, out_seas, out_trend, s2_16);
  // FFN in 2 row-chunks of 16384
  for (int c = 0; c < 2; ++c) {
    gemm_kernel<1><<<dim3(128, 16), 256, 0, stream>>>(
        s2_16 + (size_t)c*16384*512, 512, w1t, 512, h16, 2048, b1, 512);
    gemm_kernel<2><<<dim3(128, 4), 256, 0, stream>>>(
        h16, 2048, w2t, 2048, out_seas + (size_t)c*16384*512, 512, b2, 2048);
  }
}

// Round 2
// 719.399 us; speedup vs baseline: 1.3911x; 1.3911x over previous
//
#include <hip/hip_runtime.h>
#include <cstdint>
#include <cstddef>

#define NB 16
#define T_ 2048
#define D_ 512
#define F_ 2048

using f16 = _Float16;
typedef __attribute__((ext_vector_type(8))) f16 f16x8;
typedef __attribute__((ext_vector_type(4))) f16 f16x4;
typedef __attribute__((ext_vector_type(4))) float f32x4;

// ---------------- async global->LDS (16B per lane, wave-uniform LDS base) ----
__device__ __forceinline__ void g2l16(const f16* g, f16* l) {
  __builtin_amdgcn_global_load_lds((const __attribute__((address_space(1))) void*)g,
                                   (__attribute__((address_space(3))) void*)l,
                                   16, 0, 0);
}

// ---------------- 128x128 GEMM core (QKV / FFN gemms) ----------------------
__device__ __forceinline__ void gemm_core_128(
    const f16* __restrict__ Ab, int lda,
    const f16* __restrict__ Bb, int ldb,
    int K, f16* sA, f16* sB, f32x4 (&acc)[4][4])
{
  const int tid = threadIdx.x;
  const int w = tid >> 6, lane = tid & 63;
  const int o0 = (w*2+0)*1024 + lane*16;
  const int o1 = (w*2+1)*1024 + lane*16;
  const int r0 = o0 >> 6, r1 = o1 >> 6;              // row 0..127
  const int s0 = ((o0>>4)&3) ^ ((r0>>1)&3);          // pre-swizzled source slot
  const int s1 = ((o1>>4)&3) ^ ((r1>>1)&3);
  const size_t gaoff0 = (size_t)r0*lda + s0*8;
  const size_t gaoff1 = (size_t)r1*lda + s1*8;
  const size_t gboff0 = (size_t)r0*ldb + s0*8;
  const size_t gboff1 = (size_t)r1*ldb + s1*8;

  g2l16(Ab + gaoff0, sA + (w*2+0)*512);
  g2l16(Ab + gaoff1, sA + (w*2+1)*512);
  g2l16(Bb + gboff0, sB + (w*2+0)*512);
  g2l16(Bb + gboff1, sB + (w*2+1)*512);
  __syncthreads();

  const int wm = w >> 1, wn = w & 1;
  const int lr = lane & 15, ks = lane >> 4;
  int offA[4], offB[4];
  #pragma unroll
  for (int i = 0; i < 4; ++i) {
    int row = wm*64 + i*16 + lr;
    offA[i] = row*64 + ((ks ^ ((row>>1)&3)) << 4);
    int col = wn*64 + i*16 + lr;
    offB[i] = col*64 + ((ks ^ ((col>>1)&3)) << 4);
  }

  const int nk = K >> 5;
  int buf = 0;
  for (int kt = 0; kt < nk; ++kt) {
    if (kt + 1 < nk) {
      const f16* An = Ab + (kt+1)*32;
      const f16* Bn = Bb + (kt+1)*32;
      f16* dA = sA + (buf^1)*4096;
      f16* dB = sB + (buf^1)*4096;
      g2l16(An + gaoff0, dA + (w*2+0)*512);
      g2l16(An + gaoff1, dA + (w*2+1)*512);
      g2l16(Bn + gboff0, dB + (w*2+0)*512);
      g2l16(Bn + gboff1, dB + (w*2+1)*512);
    }
    const char* pA = (const char*)(sA + buf*4096);
    const char* pB = (const char*)(sB + buf*4096);
    f16x8 af[4], bf[4];
    #pragma unroll
    for (int i = 0; i < 4; ++i) {
      af[i] = *(const f16x8*)(pA + offA[i]);
      bf[i] = *(const f16x8*)(pB + offB[i]);
    }
    #pragma unroll
    for (int mi = 0; mi < 4; ++mi)
      #pragma unroll
      for (int ni = 0; ni < 4; ++ni)
        acc[mi][ni] = __builtin_amdgcn_mfma_f32_16x16x32_f16(af[mi], bf[ni], acc[mi][ni], 0, 0, 0);
    __syncthreads();
    buf ^= 1;
  }
}

// EPI: 0 = +bias -> f16 store ; 1 = +bias, exact-erf GELU -> f16 ; 2 = +bias + C(f32) -> C(f32)
template<int EPI>
__global__ __launch_bounds__(256, 2) void gemm_kernel(
    const f16* __restrict__ A, int lda,
    const f16* __restrict__ Bt, int ldb,
    void* __restrict__ Cv, int ldc,
    const float* __restrict__ bias, int K)
{
  __shared__ __align__(16) f16 sA[2*4096];
  __shared__ __align__(16) f16 sB[2*4096];
  const int m0 = blockIdx.x * 128, n0 = blockIdx.y * 128;
  f32x4 acc[4][4];
  #pragma unroll
  for (int i = 0; i < 4; ++i)
    #pragma unroll
    for (int j = 0; j < 4; ++j) acc[i][j] = f32x4{0.f, 0.f, 0.f, 0.f};
  gemm_core_128(A + (size_t)m0*lda, lda, Bt + (size_t)n0*ldb, ldb, K, sA, sB, acc);

  const int w = threadIdx.x >> 6, lane = threadIdx.x & 63;
  const int wm = w >> 1, wn = w & 1, lr = lane & 15, lq = lane >> 4;
  #pragma unroll
  for (int mi = 0; mi < 4; ++mi) {
    #pragma unroll
    for (int ni = 0; ni < 4; ++ni) {
      int col = n0 + wn*64 + ni*16 + lr;
      float bv = bias[col];
      int rbase = m0 + wm*64 + mi*16 + lq*4;
      #pragma unroll
      for (int r = 0; r < 4; ++r) {
        float val = acc[mi][ni][r] + bv;
        size_t o = (size_t)(rbase + r)*ldc + col;
        if (EPI == 0) {
          ((f16*)Cv)[o] = (f16)val;
        } else if (EPI == 1) {
          val = 0.5f * val * (1.f + erff(val * 0.70710678118654752f));
          ((f16*)Cv)[o] = (f16)val;
        } else {
          float* Cf = (float*)Cv;
          Cf[o] = Cf[o] + val;
        }
      }
    }
  }
}

// ---------------- score v2: diagonal-accumulated, deep-pipelined ------------
// Block = (b, h, g): batch b, D-half h, diagonal-group g handling
// dgA = g (16-g pairs) then dgB = 15-g (g+1 pairs) -> 17 pairs, 136 steps.
// acc accumulates across ALL pairs of a dg; ONE diag epilogue per group.
// Triple-buffered global_load_lds staging, counted vmcnt(4) (never 0 mid-loop).
__device__ __forceinline__ void diag_epilogue(float* ctile, f32x4 (&acc)[4][4],
                                              int dg, int b, float* __restrict__ score)
{
  const int tid = threadIdx.x;
  const int w = tid >> 6, lane = tid & 63;
  const int wm = w >> 1, wn = w & 1, lr = lane & 15, lq = lane >> 4;
  __builtin_amdgcn_s_barrier();          // prior ctile readers done
  #pragma unroll
  for (int mi = 0; mi < 4; ++mi) {
    #pragma unroll
    for (int ni = 0; ni < 4; ++ni) {
      int col  = wn*64 + ni*16 + lr;
      int row0 = wm*64 + mi*16 + lq*4;
      *(f32x4*)(&ctile[col*128 + row0]) = acc[mi][ni];   // ctile[col][row]
    }
  }
  asm volatile("s_waitcnt lgkmcnt(0)" ::: "memory");
  __builtin_amdgcn_s_barrier();
  if (tid < 255) {
    int delta = tid - 127;
    float sum = 0.f;
    #pragma unroll 4
    for (int rr = 0; rr < 128; ++rr) {
      int r = (rr + tid) & 127;          // stagger to avoid bank conflicts
      int c = r - delta;
      if ((unsigned)c < 128u) sum += ctile[c*128 + r];
    }
    int tau = dg*128 + delta;
    if (tau >= 1 && tau < T_) atomicAdd(&score[(size_t)b*T_ + tau], sum);
  }
  asm volatile("s_waitcnt lgkmcnt(0)" ::: "memory");
  __builtin_amdgcn_s_barrier();          // reads done before ctile reuse
}

__global__ __launch_bounds__(256, 1) void score2_kernel(
    const f16* __restrict__ qkv, float* __restrict__ score)
{
  __shared__ __align__(16) f16 stage[3*8192];   // 3 bufs x (Q 8KB + K 8KB)
  __shared__ float ctile[128*128];              // 64KB epilogue tile

  const int b = blockIdx.x, h = blockIdx.y, g = blockIdx.z;
  const int tid = threadIdx.x;
  const int w = tid >> 6, lane = tid & 63;

  // staging geometry (same as gemm_core): wave w stages rows [32w, 32w+32)
  const int o0 = (w*2+0)*1024 + lane*16;
  const int o1 = (w*2+1)*1024 + lane*16;
  const int r0 = o0 >> 6, r1 = o1 >> 6;
  const int s0 = ((o0>>4)&3) ^ ((r0>>1)&3);
  const int s1 = ((o1>>4)&3) ^ ((r1>>1)&3);
  const size_t goff0 = (size_t)r0*1536 + s0*8;
  const size_t goff1 = (size_t)r1*1536 + s1*8;
  const int l0 = (w*2+0)*512, l1 = (w*2+1)*512;

  const int nA = 16 - g;
  const int nsteps = 17*8;
  const int groupA_end = nA*8;

  // fragment read offsets (bytes within a buf half)
  const int wm = w >> 1, wn = w & 1;
  const int lr = lane & 15, ks = lane >> 4;
  int offQ[4], offK[4];
  #pragma unroll
  for (int i = 0; i < 4; ++i) {
    int row = wm*64 + i*16 + lr;
    offQ[i] = row*64 + ((ks ^ ((row>>1)&3)) << 4);
    int col = wn*64 + i*16 + lr;
    offK[i] = col*64 + ((ks ^ ((col>>1)&3)) << 4);
  }

  auto issue = [&](int sp) {
    int p = sp >> 3, kt = sp & 7;
    int ti, tj;
    if (p < nA) { tj = p; ti = p + g; }
    else        { tj = p - nA; ti = tj + 15 - g; }
    size_t qb = ((size_t)(b*T_ + ti*128))*1536 + h*256 + kt*32;
    size_t kb = ((size_t)(b*T_ + tj*128))*1536 + 512 + h*256 + kt*32;
    f16* dst = stage + (sp % 3)*8192;
    g2l16(qkv + qb + goff0, dst + l0);
    g2l16(qkv + qb + goff1, dst + l1);
    g2l16(qkv + kb + goff0, dst + 4096 + l0);
    g2l16(qkv + kb + goff1, dst + 4096 + l1);
  };

  f32x4 acc[4][4];
  #pragma unroll
  for (int i = 0; i < 4; ++i)
    #pragma unroll
    for (int j = 0; j < 4; ++j) acc[i][j] = f32x4{0.f, 0.f, 0.f, 0.f};

  issue(0);
  issue(1);
  asm volatile("s_waitcnt vmcnt(4)" ::: "memory");   // step0's 4 loads done
  __builtin_amdgcn_s_barrier();

  for (int sp = 0; sp < nsteps; ++sp) {
    // 1. ds_read fragments from buf sp%3
    const char* base = (const char*)stage + (sp % 3)*16384;
    f16x8 af[4], bf[4];
    #pragma unroll
    for (int i = 0; i < 4; ++i) {
      af[i] = *(const f16x8*)(base + offQ[i]);
      bf[i] = *(const f16x8*)(base + 8192 + offK[i]);
    }
    // 2. prefetch step sp+2 (buffer (sp+2)%3 was last read at step sp-1)
    if (sp + 2 < nsteps) issue(sp + 2);
    // 3. wait fragments
    asm volatile("s_waitcnt lgkmcnt(0)" ::: "memory");
    __builtin_amdgcn_sched_barrier(0);
    // 4. MFMA
    #pragma unroll
    for (int mi = 0; mi < 4; ++mi)
      #pragma unroll
      for (int ni = 0; ni < 4; ++ni)
        acc[mi][ni] = __builtin_amdgcn_mfma_f32_16x16x32_f16(af[mi], bf[ni], acc[mi][ni], 0, 0, 0);
    // 5. ensure next step's loads landed (keep newest 4 in flight), then barrier
    if (sp + 2 < nsteps) { asm volatile("s_waitcnt vmcnt(4)" ::: "memory"); }
    else                 { asm volatile("s_waitcnt vmcnt(0)" ::: "memory"); }
    __builtin_amdgcn_s_barrier();
    // group boundary: reduce dgA and reset accumulator
    if (sp == groupA_end - 1) {
      diag_epilogue(ctile, acc, g, b, score);
      #pragma unroll
      for (int i = 0; i < 4; ++i)
        #pragma unroll
        for (int j = 0; j < 4; ++j) acc[i][j] = f32x4{0.f, 0.f, 0.f, 0.f};
    }
  }
  diag_epilogue(ctile, acc, 15 - g, b, score);
}

__global__ void topk_kernel(const float* __restrict__ score, int* __restrict__ lags)
{
  const int b = blockIdx.x, tid = threadIdx.x;
  __shared__ float vals[T_];
  __shared__ float rmax[256];
  __shared__ int   rarg[256];
  __shared__ int   outk[8];
  for (int t = tid; t < T_; t += 256) vals[t] = (t == 0) ? -1e30f : score[(size_t)b*T_ + t];
  __syncthreads();
  for (int k = 0; k < 8; ++k) {
    float m = -1e30f; int mi = 0x7fffffff;
    for (int t = tid; t < T_; t += 256) {
      float v = vals[t];
      if (v > m || (v == m && t < mi)) { m = v; mi = t; }
    }
    rmax[tid] = m; rarg[tid] = mi;
    __syncthreads();
    for (int s = 128; s > 0; s >>= 1) {
      if (tid < s) {
        float v2 = rmax[tid+s]; int i2 = rarg[tid+s];
        if (v2 > rmax[tid] || (v2 == rmax[tid] && i2 < rarg[tid])) { rmax[tid] = v2; rarg[tid] = i2; }
      }
      __syncthreads();
    }
    if (tid == 0) { outk[k] = rarg[0]; vals[rarg[0]] = -1e30f; }
    __syncthreads();
  }
  if (tid < 8) lags[b*8 + tid] = outk[tid];
}

// trend1 = movavg25(x) -> out_trend ; s1 = x - trend1 -> f16
__global__ void decomp1_kernel(const float* __restrict__ x,
                               float* __restrict__ trend1, f16* __restrict__ s16)
{
  int idx = blockIdx.x*256 + threadIdx.x;              // (b, t, d4)
  int d4 = idx & 127, t = (idx >> 7) & (T_-1), b = idx >> 18;
  const float* xb = x + ((size_t)b*T_)*D_ + d4*4;
  f32x4 sum = {0.f,0.f,0.f,0.f};
  f32x4 center = {0.f,0.f,0.f,0.f};
  #pragma unroll
  for (int j = -12; j <= 12; ++j) {
    int tt = t + j; tt = tt < 0 ? 0 : (tt > T_-1 ? T_-1 : tt);
    f32x4 v = *(const f32x4*)(xb + (size_t)tt*D_);
    sum += v;
    if (j == 0) center = v;
  }
  f32x4 tr = sum * (1.f/25.f);
  size_t o = ((size_t)(b*T_ + t))*D_ + d4*4;
  *(f32x4*)(trend1 + o) = tr;
  f32x4 s = center - tr;
  f16x4 hv;
  #pragma unroll
  for (int i = 0; i < 4; ++i) hv[i] = (f16)s[i];
  *(f16x4*)(s16 + o) = hv;
}

// sac16 (act0, f16): trend2 = movavg25 ; s2 = sac - trend2 -> seas(f32) + s2_16 ;
// trend_io += trend2
__global__ void decomp2_kernel(const f16* __restrict__ sac,
                               float* __restrict__ seas, float* __restrict__ trend_io,
                               f16* __restrict__ s2_16)
{
  int idx = blockIdx.x*256 + threadIdx.x;
  int d4 = idx & 127, t = (idx >> 7) & (T_-1), b = idx >> 18;
  const f16* sb = sac + ((size_t)b*T_)*D_ + d4*4;
  f32x4 sum = {0.f,0.f,0.f,0.f};
  f32x4 center = {0.f,0.f,0.f,0.f};
  #pragma unroll
  for (int j = -12; j <= 12; ++j) {
    int tt = t + j; tt = tt < 0 ? 0 : (tt > T_-1 ? T_-1 : tt);
    f16x4 v = *(const f16x4*)(sb + (size_t)tt*D_);
    f32x4 vf = { (float)v[0], (float)v[1], (float)v[2], (float)v[3] };
    sum += vf;
    if (j == 0) center = vf;
  }
  f32x4 tr = sum * (1.f/25.f);
  size_t o = ((size_t)(b*T_ + t))*D_ + d4*4;
  f32x4 s = center - tr;
  *(f32x4*)(seas + o) = s;
  f16x4 hv;
  #pragma unroll
  for (int i = 0; i < 4; ++i) hv[i] = (f16)s[i];
  *(f16x4*)(s2_16 + o) = hv;
  f32x4 told = *(const f32x4*)(trend_io + o);
  *(f32x4*)(trend_io + o) = told + tr;
}

// act0 := s1_16 + (1/8) sum_k v[(t - lag_k) mod T]   (in-place, element-wise)
__global__ void gather_kernel(const f16* __restrict__ qkv, f16* __restrict__ act,
                              const int* __restrict__ lags)
{
  int idx = blockIdx.x*256 + threadIdx.x;              // (b, t, d8)
  int d8 = idx & 63, t = (idx >> 6) & (T_-1), b = idx >> 17;
  const f16* vb = qkv + (size_t)b*T_*1536 + 1024 + d8*8;
  f16* ap = act + ((size_t)(b*T_ + t))*D_ + d8*8;
  f16x8 s = *(const f16x8*)ap;
  float a[8];
  #pragma unroll
  for (int j = 0; j < 8; ++j) a[j] = (float)s[j];
  #pragma unroll
  for (int k = 0; k < 8; ++k) {
    int lag = lags[b*8 + k];
    int tt = (t - lag + T_) & (T_-1);
    f16x8 v = *(const f16x8*)(vb + (size_t)tt*1536);
    #pragma unroll
    for (int j = 0; j < 8; ++j) a[j] += 0.125f * (float)v[j];
  }
  f16x8 o;
  #pragma unroll
  for (int j = 0; j < 8; ++j) o[j] = (f16)a[j];
  *(f16x8*)ap = o;
}

// convert weights to f16, transposed to (N x K) row-major; concat qkv biases
__global__ void prepack_kernel(const float* __restrict__ Wq, const float* __restrict__ Wk,
                               const float* __restrict__ Wv, const float* __restrict__ bq,
                               const float* __restrict__ bk, const float* __restrict__ bv,
                               const float* __restrict__ W1, const float* __restrict__ W2,
                               f16* __restrict__ wcat, f16* __restrict__ w1t,
                               f16* __restrict__ w2t, float* __restrict__ bcat)
{
  int i = blockIdx.x*256 + threadIdx.x;
  if (i < 786432) {                       // wcat: 1536 x 512
    int n = i >> 9, k = i & 511;
    int sel = n >> 9, nn = n & 511;
    const float* W = sel == 0 ? Wq : (sel == 1 ? Wk : Wv);
    wcat[i] = (f16)W[k*512 + nn];
  } else if (i < 1835008) {               // w1t: 2048 x 512
    int j = i - 786432;
    int n = j >> 9, k = j & 511;
    w1t[j] = (f16)W1[k*2048 + n];
  } else if (i < 2883584) {               // w2t: 512 x 2048
    int j = i - 1835008;
    int n = j >> 11, k = j & 2047;
    w2t[j] = (f16)W2[k*512 + n];
  } else if (i < 2885120) {               // bcat: 1536
    int j = i - 2883584;
    bcat[j] = j < 512 ? bq[j] : (j < 1024 ? bk[j-512] : bv[j-1024]);
  }
}

extern "C" void kernel_launch(void* const* d_in, const int* in_sizes, int n_in,
                              void* d_out, int out_size, void* d_ws, size_t ws_size,
                              hipStream_t stream)
{
  const float* x  = (const float*)d_in[0];
  const float* Wq = (const float*)d_in[1];
  const float* bq = (const float*)d_in[2];
  const float* Wk = (const float*)d_in[3];
  const float* bk = (const float*)d_in[4];
  const float* Wv = (const float*)d_in[5];
  const float* bv = (const float*)d_in[6];
  const float* W1 = (const float*)d_in[7];
  const float* b1 = (const float*)d_in[8];
  const float* W2 = (const float*)d_in[9];
  const float* b2 = (const float*)d_in[10];

  float* out_seas  = (float*)d_out;
  float* out_trend = out_seas + (size_t)NB*T_*D_;

  char* ws = (char*)d_ws;
  f16*   act0  = (f16*)(ws);                        //  32 MB: s1_16 -> sac16 (in place)
  f16*   qkv   = (f16*)(ws + 33554432ull);          //  96 MB: [q|k|v] rows of 1536
  f16*   s2_16 = qkv;                               //  reuse (qkv dead after gather)
  f16*   h16   = (f16*)(ws + 134217728ull);         //  64 MB: FFN hidden (2 chunks)
  f16*   wcat  = (f16*)(ws + 201326592ull);
  f16*   w1t   = (f16*)(ws + 202899456ull);
  f16*   w2t   = (f16*)(ws + 204996608ull);
  float* bcat  = (float*)(ws + 207093760ull);
  float* score = (float*)(ws + 207099904ull);
  int*   lags  = (int*)(ws + 207230976ull);

  (void)hipMemsetAsync(score, 0, (size_t)NB*T_*sizeof(float), stream);
  prepack_kernel<<<11270, 256, 0, stream>>>(Wq, Wk, Wv, bq, bk, bv, W1, W2,
                                            wcat, w1t, w2t, bcat);
  decomp1_kernel<<<NB*T_*(D_/4)/256, 256, 0, stream>>>(x, out_trend, act0);
  // QKV: (32768 x 512) @ (512 x 1536) -> qkv f16
  gemm_kernel<0><<<dim3(32768/128, 1536/128), 256, 0, stream>>>(
      act0, 512, wcat, 512, qkv, 1536, bcat, 512);
  score2_kernel<<<dim3(16, 2, 8), 256, 0, stream>>>(qkv, score);
  topk_kernel<<<NB, 256, 0, stream>>>(score, lags);
  gather_kernel<<<NB*T_*(D_/8)/256, 256, 0, stream>>>(qkv, act0, lags);
  decomp2_kernel<<<NB*T_*(D_/4)/256, 256, 0, stream>>>(act0, out_seas, out_trend, s2_16);
  // FFN in 2 row-chunks of 16384
  for (int c = 0; c < 2; ++c) {
    gemm_kernel<1><<<dim3(128, 16), 256, 0, stream>>>(
        s2_16 + (size_t)c*16384*512, 512, w1t, 512, h16, 2048, b1, 512);
    gemm_kernel<2><<<dim3(128, 4), 256, 0, stream>>>(
        h16, 2048, w2t, 2048, out_seas + (size_t)c*16384*512, 512, b2, 2048);
  }
}

// Round 3
// 651.902 us; speedup vs baseline: 1.5351x; 1.1035x over previous
//
#include <hip/hip_runtime.h>
#include <cstdint>
#include <cstddef>

#define NB 16
#define T_ 2048
#define D_ 512
#define F_ 2048

using f16 = _Float16;
typedef __attribute__((ext_vector_type(8))) f16 f16x8;
typedef __attribute__((ext_vector_type(4))) f16 f16x4;
typedef __attribute__((ext_vector_type(4))) float f32x4;

// ---------------- async global->LDS (16B per lane, wave-uniform LDS base) ----
__device__ __forceinline__ void g2l16(const f16* g, f16* l) {
  __builtin_amdgcn_global_load_lds((const __attribute__((address_space(1))) void*)g,
                                   (__attribute__((address_space(3))) void*)l,
                                   16, 0, 0);
}

// ---------------- 128x128 GEMM core, BK=64, counted-vmcnt double buffer -----
// LDS per buffer: A [128][64] f16 (16KB) @0, B [128][64] f16 @16KB. 2 buffers
// (64KB total) -> 2 blocks/CU. 8-slot XOR swizzle (slot ^= row&7): b128 frag
// reads are conflict-free (8 lanes/slot = LDS minimum). Source pre-swizzled
// for linear global_load_lds dest (rule #21). vmcnt(8) keeps the next tile's
// 8 loads in flight across barriers; never drains to 0 mid-loop (T4).
__device__ __forceinline__ void gemm_bk64(
    const f16* __restrict__ Ab, int lda,
    const f16* __restrict__ Bb, int ldb,
    int K, f16* sbuf, f32x4 (&acc)[4][4])
{
  const int tid = threadIdx.x;
  const int w = tid >> 6, lane = tid & 63;
  int ldsOff[4];
  size_t gA[4], gB[4];
  #pragma unroll
  for (int i = 0; i < 4; ++i) {
    int o = (i*4 + w)*1024 + lane*16;        // byte offset in 16KB half-tile
    int row = o >> 7;                        // 128B rows
    int slot = (o >> 4) & 7;
    int ss = slot ^ (row & 7);               // pre-swizzled source slot
    ldsOff[i] = o;
    gA[i] = (size_t)row*lda + ss*8;
    gB[i] = (size_t)row*ldb + ss*8;
  }
  const int wm = w >> 1, wn = w & 1;
  const int lr = lane & 15, ks = lane >> 4;
  int offA[4][2], offB[4][2];
  #pragma unroll
  for (int i = 0; i < 4; ++i) {
    int rowA = wm*64 + i*16 + lr;
    int colB = wn*64 + i*16 + lr;
    #pragma unroll
    for (int j = 0; j < 2; ++j) {
      offA[i][j] = rowA*128 + ((((j*4+ks)) ^ (rowA & 7)) << 4);
      offB[i][j] = colB*128 + ((((j*4+ks)) ^ (colB & 7)) << 4);
    }
  }
  const int nk = K >> 6;
  // prologue: stage tile 0 -> buf 0
  #pragma unroll
  for (int i = 0; i < 4; ++i) {
    g2l16(Ab + gA[i], (f16*)((char*)sbuf + ldsOff[i]));
    g2l16(Bb + gB[i], (f16*)((char*)sbuf + 16384 + ldsOff[i]));
  }
  for (int kt = 0; kt < nk; ++kt) {
    const int cur = kt & 1;
    if (kt + 1 < nk) {
      const f16* An = Ab + (kt+1)*64;
      const f16* Bn = Bb + (kt+1)*64;
      char* dst = (char*)sbuf + (cur^1)*32768;
      #pragma unroll
      for (int i = 0; i < 4; ++i) {
        g2l16(An + gA[i], (f16*)(dst + ldsOff[i]));
        g2l16(Bn + gB[i], (f16*)(dst + 16384 + ldsOff[i]));
      }
      asm volatile("s_waitcnt vmcnt(8)" ::: "memory");   // tile kt landed
    } else {
      asm volatile("s_waitcnt vmcnt(0)" ::: "memory");
    }
    __builtin_amdgcn_s_barrier();
    __builtin_amdgcn_sched_barrier(0);
    const char* pA = (const char*)sbuf + cur*32768;
    const char* pB = pA + 16384;
    f16x8 af[4][2], bf[4][2];
    #pragma unroll
    for (int i = 0; i < 4; ++i)
      #pragma unroll
      for (int j = 0; j < 2; ++j) {
        af[i][j] = *(const f16x8*)(pA + offA[i][j]);
        bf[i][j] = *(const f16x8*)(pB + offB[i][j]);
      }
    #pragma unroll
    for (int j = 0; j < 2; ++j)
      #pragma unroll
      for (int mi = 0; mi < 4; ++mi)
        #pragma unroll
        for (int ni = 0; ni < 4; ++ni)
          acc[mi][ni] = __builtin_amdgcn_mfma_f32_16x16x32_f16(af[mi][j], bf[ni][j], acc[mi][ni], 0, 0, 0);
    __builtin_amdgcn_sched_barrier(0);
    __builtin_amdgcn_s_barrier();          // all reads of cur^1 done before next prefetch
  }
}

// EPI: 0 = +bias -> f16 store ; 1 = +bias, exact-erf GELU -> f16 ; 2 = +bias + C(f32) -> C(f32)
template<int EPI>
__global__ __launch_bounds__(256, 2) void gemm_kernel(
    const f16* __restrict__ A, int lda,
    const f16* __restrict__ Bt, int ldb,
    void* __restrict__ Cv, int ldc,
    const float* __restrict__ bias, int K, int nN)
{
  __shared__ __align__(16) f16 sbuf[2*16384];          // 64KB
  // bijective XCD swizzle (gridDim.x % 8 == 0), n-fast decode
  const int nwg = gridDim.x, wg = blockIdx.x;
  const int cpx = nwg >> 3;
  const int swz = (wg & 7)*cpx + (wg >> 3);
  const int n0 = (swz % nN) * 128;
  const int m0 = (swz / nN) * 128;
  f32x4 acc[4][4];
  #pragma unroll
  for (int i = 0; i < 4; ++i)
    #pragma unroll
    for (int j = 0; j < 4; ++j) acc[i][j] = f32x4{0.f, 0.f, 0.f, 0.f};
  gemm_bk64(A + (size_t)m0*lda, lda, Bt + (size_t)n0*ldb, ldb, K, sbuf, acc);

  const int w = threadIdx.x >> 6, lane = threadIdx.x & 63;
  const int wm = w >> 1, wn = w & 1, lr = lane & 15, lq = lane >> 4;
  #pragma unroll
  for (int mi = 0; mi < 4; ++mi) {
    #pragma unroll
    for (int ni = 0; ni < 4; ++ni) {
      int col = n0 + wn*64 + ni*16 + lr;
      float bv = bias[col];
      int rbase = m0 + wm*64 + mi*16 + lq*4;
      #pragma unroll
      for (int r = 0; r < 4; ++r) {
        float val = acc[mi][ni][r] + bv;
        size_t o = (size_t)(rbase + r)*ldc + col;
        if (EPI == 0) {
          ((f16*)Cv)[o] = (f16)val;
        } else if (EPI == 1) {
          val = 0.5f * val * (1.f + erff(val * 0.70710678118654752f));
          ((f16*)Cv)[o] = (f16)val;
        } else {
          float* Cf = (float*)Cv;
          Cf[o] = Cf[o] + val;
        }
      }
    }
  }
}

// ---------------- score v3: diagonal-accumulated, D-quartered, 2 blocks/CU --
// Block = (b, h, g): batch b, D-quarter h (128 ch), diagonal-group g:
// dgA = g (16-g pairs) then dgB = 15-g (g+1 pairs) -> 17 pairs x 4 K-steps.
// Triple-buffered BK=32 staging (48KB) + 32KB half-ctile epilogue = 80KB.
__device__ __forceinline__ void diag_epilogue2(float* ctile, f32x4 (&acc)[4][4],
                                               int dg, int b, float* __restrict__ score)
{
  const int tid = threadIdx.x;
  const int w = tid >> 6, lane = tid & 63;
  const int wm = w >> 1, wn = w & 1, lr = lane & 15, lq = lane >> 4;
  float total = 0.f;
  #pragma unroll
  for (int pass = 0; pass < 2; ++pass) {
    __builtin_amdgcn_s_barrier();                 // ctile free
    if (wn == pass) {
      #pragma unroll
      for (int mi = 0; mi < 4; ++mi) {
        #pragma unroll
        for (int ni = 0; ni < 4; ++ni) {
          int colL = ni*16 + lr;                  // local col 0..63
          int row0 = wm*64 + mi*16 + lq*4;
          *(f32x4*)(&ctile[colL*128 + row0]) = acc[mi][ni];
        }
      }
    }
    asm volatile("s_waitcnt lgkmcnt(0)" ::: "memory");
    __builtin_amdgcn_s_barrier();
    if (tid < 255) {
      int delta = tid - 127;
      #pragma unroll 8
      for (int cc = 0; cc < 64; ++cc) {
        int r = pass*64 + cc + delta;             // r - c = delta
        if ((unsigned)r < 128u) total += ctile[cc*128 + r];
      }
    }
    asm volatile("s_waitcnt lgkmcnt(0)" ::: "memory");
  }
  __builtin_amdgcn_s_barrier();
  if (tid < 255) {
    int tau = dg*128 + (tid - 127);
    if (tau >= 1 && tau < T_) atomicAdd(&score[(size_t)b*T_ + tau], total);
  }
}

__global__ __launch_bounds__(256, 2) void score2_kernel(
    const f16* __restrict__ qkv, float* __restrict__ score)
{
  __shared__ __align__(16) f16 stage[3*8192];   // 3 bufs x (Q 8KB + K 8KB)
  __shared__ float ctile[64*128];               // 32KB epilogue half-tile

  const int b = blockIdx.x, h = blockIdx.y, g = blockIdx.z;
  const int tid = threadIdx.x;
  const int w = tid >> 6, lane = tid & 63;

  const int o0 = (w*2+0)*1024 + lane*16;
  const int o1 = (w*2+1)*1024 + lane*16;
  const int r0 = o0 >> 6, r1 = o1 >> 6;
  const int s0 = ((o0>>4)&3) ^ ((r0>>1)&3);
  const int s1 = ((o1>>4)&3) ^ ((r1>>1)&3);
  const size_t goff0 = (size_t)r0*1536 + s0*8;
  const size_t goff1 = (size_t)r1*1536 + s1*8;
  const int l0 = (w*2+0)*512, l1 = (w*2+1)*512;

  const int nA = 16 - g;
  const int nsteps = 17*4;
  const int groupA_end = nA*4;

  const int wm = w >> 1, wn = w & 1;
  const int lr = lane & 15, ks = lane >> 4;
  int offQ[4], offK[4];
  #pragma unroll
  for (int i = 0; i < 4; ++i) {
    int row = wm*64 + i*16 + lr;
    offQ[i] = row*64 + ((ks ^ ((row>>1)&3)) << 4);
    int col = wn*64 + i*16 + lr;
    offK[i] = col*64 + ((ks ^ ((col>>1)&3)) << 4);
  }

  auto issue = [&](int sp) {
    int p = sp >> 2, kt = sp & 3;
    int ti, tj;
    if (p < nA) { tj = p; ti = p + g; }
    else        { tj = p - nA; ti = tj + 15 - g; }
    size_t qb = ((size_t)(b*T_ + ti*128))*1536 + h*128 + kt*32;
    size_t kb = ((size_t)(b*T_ + tj*128))*1536 + 512 + h*128 + kt*32;
    f16* dst = stage + (sp % 3)*8192;
    g2l16(qkv + qb + goff0, dst + l0);
    g2l16(qkv + qb + goff1, dst + l1);
    g2l16(qkv + kb + goff0, dst + 4096 + l0);
    g2l16(qkv + kb + goff1, dst + 4096 + l1);
  };

  f32x4 acc[4][4];
  #pragma unroll
  for (int i = 0; i < 4; ++i)
    #pragma unroll
    for (int j = 0; j < 4; ++j) acc[i][j] = f32x4{0.f, 0.f, 0.f, 0.f};

  issue(0);
  issue(1);
  asm volatile("s_waitcnt vmcnt(4)" ::: "memory");
  __builtin_amdgcn_s_barrier();

  for (int sp = 0; sp < nsteps; ++sp) {
    const char* base = (const char*)stage + (sp % 3)*16384;
    f16x8 af[4], bf[4];
    #pragma unroll
    for (int i = 0; i < 4; ++i) {
      af[i] = *(const f16x8*)(base + offQ[i]);
      bf[i] = *(const f16x8*)(base + 8192 + offK[i]);
    }
    if (sp + 2 < nsteps) issue(sp + 2);
    asm volatile("s_waitcnt lgkmcnt(0)" ::: "memory");
    __builtin_amdgcn_sched_barrier(0);
    #pragma unroll
    for (int mi = 0; mi < 4; ++mi)
      #pragma unroll
      for (int ni = 0; ni < 4; ++ni)
        acc[mi][ni] = __builtin_amdgcn_mfma_f32_16x16x32_f16(af[mi], bf[ni], acc[mi][ni], 0, 0, 0);
    if (sp + 2 < nsteps) { asm volatile("s_waitcnt vmcnt(4)" ::: "memory"); }
    else                 { asm volatile("s_waitcnt vmcnt(0)" ::: "memory"); }
    __builtin_amdgcn_s_barrier();
    if (sp == groupA_end - 1) {
      diag_epilogue2(ctile, acc, g, b, score);
      #pragma unroll
      for (int i = 0; i < 4; ++i)
        #pragma unroll
        for (int j = 0; j < 4; ++j) acc[i][j] = f32x4{0.f, 0.f, 0.f, 0.f};
    }
  }
  diag_epilogue2(ctile, acc, 15 - g, b, score);
}

__global__ void topk_kernel(const float* __restrict__ score, int* __restrict__ lags)
{
  const int b = blockIdx.x, tid = threadIdx.x;
  __shared__ float vals[T_];
  __shared__ float rmax[256];
  __shared__ int   rarg[256];
  __shared__ int   outk[8];
  for (int t = tid; t < T_; t += 256) vals[t] = (t == 0) ? -1e30f : score[(size_t)b*T_ + t];
  __syncthreads();
  for (int k = 0; k < 8; ++k) {
    float m = -1e30f; int mi = 0x7fffffff;
    for (int t = tid; t < T_; t += 256) {
      float v = vals[t];
      if (v > m || (v == m && t < mi)) { m = v; mi = t; }
    }
    rmax[tid] = m; rarg[tid] = mi;
    __syncthreads();
    for (int s = 128; s > 0; s >>= 1) {
      if (tid < s) {
        float v2 = rmax[tid+s]; int i2 = rarg[tid+s];
        if (v2 > rmax[tid] || (v2 == rmax[tid] && i2 < rarg[tid])) { rmax[tid] = v2; rarg[tid] = i2; }
      }
      __syncthreads();
    }
    if (tid == 0) { outk[k] = rarg[0]; vals[rarg[0]] = -1e30f; }
    __syncthreads();
  }
  if (tid < 8) lags[b*8 + tid] = outk[tid];
}

// trend1 = movavg25(x) -> out_trend ; s1 = x - trend1 -> f16
__global__ void decomp1_kernel(const float* __restrict__ x,
                               float* __restrict__ trend1, f16* __restrict__ s16)
{
  int idx = blockIdx.x*256 + threadIdx.x;              // (b, t, d4)
  int d4 = idx & 127, t = (idx >> 7) & (T_-1), b = idx >> 18;
  const float* xb = x + ((size_t)b*T_)*D_ + d4*4;
  f32x4 sum = {0.f,0.f,0.f,0.f};
  f32x4 center = {0.f,0.f,0.f,0.f};
  #pragma unroll
  for (int j = -12; j <= 12; ++j) {
    int tt = t + j; tt = tt < 0 ? 0 : (tt > T_-1 ? T_-1 : tt);
    f32x4 v = *(const f32x4*)(xb + (size_t)tt*D_);
    sum += v;
    if (j == 0) center = v;
  }
  f32x4 tr = sum * (1.f/25.f);
  size_t o = ((size_t)(b*T_ + t))*D_ + d4*4;
  *(f32x4*)(trend1 + o) = tr;
  f32x4 s = center - tr;
  f16x4 hv;
  #pragma unroll
  for (int i = 0; i < 4; ++i) hv[i] = (f16)s[i];
  *(f16x4*)(s16 + o) = hv;
}

// sac16 (act0, f16): trend2 = movavg25 ; s2 = sac - trend2 -> seas(f32) + s2_16 ;
// trend_io += trend2
__global__ void decomp2_kernel(const f16* __restrict__ sac,
                               float* __restrict__ seas, float* __restrict__ trend_io,
                               f16* __restrict__ s2_16)
{
  int idx = blockIdx.x*256 + threadIdx.x;
  int d4 = idx & 127, t = (idx >> 7) & (T_-1), b = idx >> 18;
  const f16* sb = sac + ((size_t)b*T_)*D_ + d4*4;
  f32x4 sum = {0.f,0.f,0.f,0.f};
  f32x4 center = {0.f,0.f,0.f,0.f};
  #pragma unroll
  for (int j = -12; j <= 12; ++j) {
    int tt = t + j; tt = tt < 0 ? 0 : (tt > T_-1 ? T_-1 : tt);
    f16x4 v = *(const f16x4*)(sb + (size_t)tt*D_);
    f32x4 vf = { (float)v[0], (float)v[1], (float)v[2], (float)v[3] };
    sum += vf;
    if (j == 0) center = vf;
  }
  f32x4 tr = sum * (1.f/25.f);
  size_t o = ((size_t)(b*T_ + t))*D_ + d4*4;
  f32x4 s = center - tr;
  *(f32x4*)(seas + o) = s;
  f16x4 hv;
  #pragma unroll
  for (int i = 0; i < 4; ++i) hv[i] = (f16)s[i];
  *(f16x4*)(s2_16 + o) = hv;
  f32x4 told = *(const f32x4*)(trend_io + o);
  *(f32x4*)(trend_io + o) = told + tr;
}

// act0 := s1_16 + (1/8) sum_k v[(t - lag_k) mod T]   (in-place, element-wise)
__global__ void gather_kernel(const f16* __restrict__ qkv, f16* __restrict__ act,
                              const int* __restrict__ lags)
{
  int idx = blockIdx.x*256 + threadIdx.x;              // (b, t, d8)
  int d8 = idx & 63, t = (idx >> 6) & (T_-1), b = idx >> 17;
  const f16* vb = qkv + (size_t)b*T_*1536 + 1024 + d8*8;
  f16* ap = act + ((size_t)(b*T_ + t))*D_ + d8*8;
  f16x8 s = *(const f16x8*)ap;
  float a[8];
  #pragma unroll
  for (int j = 0; j < 8; ++j) a[j] = (float)s[j];
  #pragma unroll
  for (int k = 0; k < 8; ++k) {
    int lag = lags[b*8 + k];
    int tt = (t - lag + T_) & (T_-1);
    f16x8 v = *(const f16x8*)(vb + (size_t)tt*1536);
    #pragma unroll
    for (int j = 0; j < 8; ++j) a[j] += 0.125f * (float)v[j];
  }
  f16x8 o;
  #pragma unroll
  for (int j = 0; j < 8; ++j) o[j] = (f16)a[j];
  *(f16x8*)ap = o;
}

// convert weights to f16, transposed to (N x K) row-major; concat qkv biases
__global__ void prepack_kernel(const float* __restrict__ Wq, const float* __restrict__ Wk,
                               const float* __restrict__ Wv, const float* __restrict__ bq,
                               const float* __restrict__ bk, const float* __restrict__ bv,
                               const float* __restrict__ W1, const float* __restrict__ W2,
                               f16* __restrict__ wcat, f16* __restrict__ w1t,
                               f16* __restrict__ w2t, float* __restrict__ bcat)
{
  int i = blockIdx.x*256 + threadIdx.x;
  if (i < 786432) {                       // wcat: 1536 x 512
    int n = i >> 9, k = i & 511;
    int sel = n >> 9, nn = n & 511;
    const float* W = sel == 0 ? Wq : (sel == 1 ? Wk : Wv);
    wcat[i] = (f16)W[k*512 + nn];
  } else if (i < 1835008) {               // w1t: 2048 x 512
    int j = i - 786432;
    int n = j >> 9, k = j & 511;
    w1t[j] = (f16)W1[k*2048 + n];
  } else if (i < 2883584) {               // w2t: 512 x 2048
    int j = i - 1835008;
    int n = j >> 11, k = j & 2047;
    w2t[j] = (f16)W2[k*512 + n];
  } else if (i < 2885120) {               // bcat: 1536
    int j = i - 2883584;
    bcat[j] = j < 512 ? bq[j] : (j < 1024 ? bk[j-512] : bv[j-1024]);
  }
}

extern "C" void kernel_launch(void* const* d_in, const int* in_sizes, int n_in,
                              void* d_out, int out_size, void* d_ws, size_t ws_size,
                              hipStream_t stream)
{
  const float* x  = (const float*)d_in[0];
  const float* Wq = (const float*)d_in[1];
  const float* bq = (const float*)d_in[2];
  const float* Wk = (const float*)d_in[3];
  const float* bk = (const float*)d_in[4];
  const float* Wv = (const float*)d_in[5];
  const float* bv = (const float*)d_in[6];
  const float* W1 = (const float*)d_in[7];
  const float* b1 = (const float*)d_in[8];
  const float* W2 = (const float*)d_in[9];
  const float* b2 = (const float*)d_in[10];

  float* out_seas  = (float*)d_out;
  float* out_trend = out_seas + (size_t)NB*T_*D_;

  char* ws = (char*)d_ws;
  f16*   act0  = (f16*)(ws);                        //  32 MB
  f16*   qkv   = (f16*)(ws + 33554432ull);          //  96 MB
  f16*   s2_16 = qkv;                               //  reuse (qkv dead after gather)
  f16*   h16   = (f16*)(ws + 134217728ull);         //  64 MB
  f16*   wcat  = (f16*)(ws + 201326592ull);
  f16*   w1t   = (f16*)(ws + 202899456ull);
  f16*   w2t   = (f16*)(ws + 204996608ull);
  float* bcat  = (float*)(ws + 207093760ull);
  float* score = (float*)(ws + 207099904ull);
  int*   lags  = (int*)(ws + 207230976ull);

  (void)hipMemsetAsync(score, 0, (size_t)NB*T_*sizeof(float), stream);
  prepack_kernel<<<11270, 256, 0, stream>>>(Wq, Wk, Wv, bq, bk, bv, W1, W2,
                                            wcat, w1t, w2t, bcat);
  decomp1_kernel<<<NB*T_*(D_/4)/256, 256, 0, stream>>>(x, out_trend, act0);
  // QKV: (32768 x 512) @ (512 x 1536) -> qkv f16   [256 m-tiles x 12 n-tiles]
  gemm_kernel<0><<<256*12, 256, 0, stream>>>(act0, 512, wcat, 512, qkv, 1536, bcat, 512, 12);
  score2_kernel<<<dim3(16, 4, 8), 256, 0, stream>>>(qkv, score);
  topk_kernel<<<NB, 256, 0, stream>>>(score, lags);
  gather_kernel<<<NB*T_*(D_/8)/256, 256, 0, stream>>>(qkv, act0, lags);
  decomp2_kernel<<<NB*T_*(D_/4)/256, 256, 0, stream>>>(act0, out_seas, out_trend, s2_16);
  // FFN in 2 row-chunks of 16384 rows
  for (int c = 0; c < 2; ++c) {
    gemm_kernel<1><<<128*16, 256, 0, stream>>>(
        s2_16 + (size_t)c*16384*512, 512, w1t, 512, h16, 2048, b1, 512, 16);
    gemm_kernel<2><<<128*4, 256, 0, stream>>>(
        h16, 2048, w2t, 2048, out_seas + (size_t)c*16384*512, 512, b2, 2048, 4);
  }
}